// Round 3
// baseline (4780.985 us; speedup 1.0000x reference)
//
#include <hip/hip_runtime.h>
#include <hip/hip_bf16.h>

#define NN 400000
#define EE 1600000
#define NB 8192

// ---------- segment bounds: start[b] = lower_bound(batch, b); batch is sorted ----------
__global__ void k_seg(const int* __restrict__ batch, int* __restrict__ start){
  int b = blockIdx.x*256 + threadIdx.x;
  if (b > NB) return;
  int lo = 0, hi = NN;
  while (lo < hi){ int mid = (lo+hi)>>1; if (batch[mid] < b) lo = mid+1; else hi = mid; }
  start[b] = lo;
}

// ---------- gate MLP: g[i] = relu(x@W1 + b1) @ W2 + b2  (wave per node) ----------
__global__ __launch_bounds__(256) void k_gate(const float* __restrict__ x,
    const float* __restrict__ W1, const float* __restrict__ b1,
    const float* __restrict__ W2, const float* __restrict__ b2,
    float* __restrict__ g){
  __shared__ float sW1[64*64];
  __shared__ float sB[128];     // [0:64)=b1, [64:128)=W2
  int tid = threadIdx.x;
  for (int i = tid; i < 4096; i += 256) sW1[i] = W1[i];
  if (tid < 64) sB[tid] = b1[tid];
  else if (tid < 128) sB[tid] = W2[tid-64];
  __syncthreads();
  int lane = tid & 63;
  int node = (blockIdx.x<<2) + (tid>>6);
  float xv = x[(size_t)node*64 + lane];
  float y = 0.f;
  #pragma unroll
  for (int k = 0; k < 64; ++k)
    y = fmaf(__shfl(xv, k), sW1[k*64 + lane], y);   // lane j accumulates col j
  float t = fmaxf(y + sB[lane], 0.f) * sB[64+lane];
  #pragma unroll
  for (int off = 32; off; off >>= 1) t += __shfl_xor(t, off);
  if (lane == 0) g[node] = t + b2[0];
}

// ---------- attention pool: one wave per graph (segments contiguous: batch sorted) ----------
__global__ __launch_bounds__(64) void k_att(const float* __restrict__ x, const float* __restrict__ g,
    const int* __restrict__ start, float* __restrict__ att){
  int b = blockIdx.x, lane = threadIdx.x;
  int s0 = start[b], s1 = start[b+1];
  if (s1 <= s0){ att[b*64+lane] = 0.f; return; }
  float m = -3.0e38f;
  for (int i = s0+lane; i < s1; i += 64) m = fmaxf(m, g[i]);
  #pragma unroll
  for (int off = 32; off; off >>= 1) m = fmaxf(m, __shfl_xor(m, off));
  float s = 0.f;
  for (int i = s0+lane; i < s1; i += 64) s += expf(g[i]-m);
  #pragma unroll
  for (int off = 32; off; off >>= 1) s += __shfl_xor(s, off);
  float acc = 0.f;
  for (int i = s0; i < s1; ++i)                       // lane = feature
    acc = fmaf(expf(g[i]-m), x[(size_t)i*64+lane], acc);
  att[b*64+lane] = acc / s;
}

// ---------- CSR build (per side, reused for all 3 layers) ----------
__global__ void k_zero(int* __restrict__ degI, int* __restrict__ gc){
  int i = blockIdx.x*256 + threadIdx.x;
  if (i < NN) degI[i] = 0;
  if (i == 0) *gc = 0;
}
__global__ void k_count(const int* __restrict__ dst, int* __restrict__ degI){
  int e = blockIdx.x*256 + threadIdx.x;
  if (e < EE) atomicAdd(&degI[dst[e]], 1);
}
// bucket allocation: wave-level prefix scan, one global atomic per wave
__global__ __launch_bounds__(256) void k_alloc(const int* __restrict__ degI, int* __restrict__ gc,
    int* __restrict__ base, int* __restrict__ cursor, float* __restrict__ dinv){
  int i = blockIdx.x*256 + threadIdx.x;
  int lane = threadIdx.x & 63;
  int d = (i < NN) ? degI[i] : 0;
  int incl = d;
  #pragma unroll
  for (int off = 1; off < 64; off <<= 1){
    int t = __shfl_up(incl, off);
    if (lane >= off) incl += t;
  }
  int waveTotal = __shfl(incl, 63);
  int wbase = 0;
  if (lane == 63) wbase = atomicAdd(gc, waveTotal);
  wbase = __shfl(wbase, 63);
  if (i < NN){
    int b = wbase + incl - d;   // exclusive offset within wave
    base[i] = b; cursor[i] = b;
    dinv[i] = 1.f / sqrtf((float)d + 1.f);   // +1 self loop
  }
}
__global__ void k_fillcsr(const int* __restrict__ src, const int* __restrict__ dst,
                          int* __restrict__ cursor, int* __restrict__ csr){
  int e = blockIdx.x*256 + threadIdx.x;
  if (e >= EE) return;
  int p = atomicAdd(&cursor[dst[e]], 1);
  csr[p] = src[e];
}

// ---------- tall-skinny GEMM: out[N,96] = in[N,K] @ W[K,96]; relu fused on read ----------
// 64-row x 96-col tile / block of 256; 4x6 micro-tile per thread.
template<int K, bool RELU>
__global__ __launch_bounds__(256) void k_gemm(const float* __restrict__ in,
    const float* __restrict__ W, float* __restrict__ out){
  __shared__ float sIn[K*68];   // transposed [k][row], pad 68: aligned b128 reads, spread write banks
  __shared__ float sW[K*96];
  const int tid = threadIdx.x;
  const int r0 = blockIdx.x << 6;
  for (int i = tid; i < K*96; i += 256) sW[i] = W[i];
  for (int i = tid; i < 64*K; i += 256){   // i = linear index into contiguous 64xK tile -> coalesced
    int r = i / K, k = i - r*K;
    float v = in[(size_t)r0*K + i];
    if (RELU) v = fmaxf(v, 0.f);
    sIn[k*68 + r] = v;
  }
  __syncthreads();
  const int tx = tid & 15;   // cols tx*6 .. +5
  const int ty = tid >> 4;   // rows ty*4 .. +3
  float acc[4][6];
  #pragma unroll
  for (int i = 0; i < 4; ++i)
    #pragma unroll
    for (int j = 0; j < 6; ++j) acc[i][j] = 0.f;
  for (int k = 0; k < K; ++k){
    float a[4], w[6];
    #pragma unroll
    for (int i = 0; i < 4; ++i) a[i] = sIn[k*68 + ty*4 + i];
    #pragma unroll
    for (int j = 0; j < 6; ++j) w[j] = sW[k*96 + tx*6 + j];
    #pragma unroll
    for (int i = 0; i < 4; ++i)
      #pragma unroll
      for (int j = 0; j < 6; ++j)
        acc[i][j] = fmaf(a[i], w[j], acc[i][j]);
  }
  #pragma unroll
  for (int i = 0; i < 4; ++i){
    size_t row = r0 + ty*4 + i;
    #pragma unroll
    for (int j = 0; j < 6; ++j)
      out[row*96 + tx*6 + j] = acc[i][j];
  }
}

// ---------- GCN aggregation by gather: out[i] = b + dinv[i]^2*xw[i] + sum_e dinv[i]dinv[s]*xw[s] ----------
__global__ __launch_bounds__(384) void k_gather(const float* __restrict__ xw,
    const int* __restrict__ csr, const int* __restrict__ base, const int* __restrict__ degI,
    const float* __restrict__ dinv, const float* __restrict__ bias, float* __restrict__ out){
  int i = (blockIdx.x<<2) + threadIdx.y;
  int f = threadIdx.x;                       // 0..95, coalesced
  float di = dinv[i];
  float acc = fmaf(di*di, xw[(size_t)i*96+f], bias[f]);
  int b0 = base[i], cnt = degI[i];
  for (int t = 0; t < cnt; ++t){
    int s = csr[b0+t];                       // broadcast across lanes
    acc = fmaf(di*dinv[s], xw[(size_t)s*96+f], acc);
  }
  out[(size_t)i*96+f] = acc;
}

// ---------- mean pool ----------
__global__ __launch_bounds__(128) void k_mean(const float* __restrict__ h,
    const int* __restrict__ start, float* __restrict__ mean){
  int b = blockIdx.x, f = threadIdx.x;
  if (f >= 96) return;
  int s0 = start[b], s1 = start[b+1];
  float acc = 0.f;
  for (int i = s0; i < s1; ++i) acc += h[(size_t)i*96+f];
  mean[b*96+f] = acc / fmaxf((float)(s1-s0), 1.f);
}

// ---------- final MLP: relu(cat@W0+b0)@W1+b1 ; fp32 output ----------
__global__ __launch_bounds__(128) void k_final(const float* __restrict__ meanP, const float* __restrict__ meanD,
    const float* __restrict__ attP, const float* __restrict__ attD,
    const float* __restrict__ W0, const float* __restrict__ b0,
    const float* __restrict__ W1, const float* __restrict__ b1,
    float* __restrict__ out){
  __shared__ float cat[320];
  __shared__ float hb[96];
  int b = blockIdx.x, tid = threadIdx.x;
  if (tid < 96){ cat[tid] = meanP[b*96+tid]; cat[96+tid] = meanD[b*96+tid]; }
  if (tid < 64){ cat[192+tid] = attP[b*64+tid]; cat[256+tid] = attD[b*64+tid]; }
  __syncthreads();
  if (tid < 96){
    float acc = b0[tid];
    for (int k = 0; k < 320; ++k) acc = fmaf(cat[k], W0[k*96+tid], acc);
    hb[tid] = fmaxf(acc, 0.f) * W1[tid];
  }
  __syncthreads();
  if (tid == 0){
    float y = b1[0];
    for (int j = 0; j < 96; ++j) y += hb[j];
    out[b] = y;
  }
}

extern "C" void kernel_launch(void* const* d_in, const int* in_sizes, int n_in,
                              void* d_out, int out_size, void* d_ws, size_t ws_size,
                              hipStream_t stream){
  const float* x_p = (const float*)d_in[0];
  const float* x_d = (const float*)d_in[1];
  // d_in[2], d_in[3]: edge_attr -- unused by GCNConv
  const int* ei_p = (const int*)d_in[4];    // [2,E]: row0 src, row1 dst
  const int* ei_d = (const int*)d_in[5];
  const int* batch_p = (const int*)d_in[6];
  const int* batch_d = (const int*)d_in[7];
  const float* gW1 = (const float*)d_in[8];
  const float* gb1 = (const float*)d_in[9];
  const float* gW2 = (const float*)d_in[10];
  const float* gb2 = (const float*)d_in[11];
  const float* cW[2][3] = {{(const float*)d_in[12],(const float*)d_in[14],(const float*)d_in[16]},
                           {(const float*)d_in[18],(const float*)d_in[20],(const float*)d_in[22]}};
  const float* cB[2][3] = {{(const float*)d_in[13],(const float*)d_in[15],(const float*)d_in[17]},
                           {(const float*)d_in[19],(const float*)d_in[21],(const float*)d_in[23]}};
  const float* lW0 = (const float*)d_in[24];
  const float* lb0 = (const float*)d_in[25];
  const float* lW1 = (const float*)d_in[26];
  const float* lb1 = (const float*)d_in[27];
  float* out = (float*)d_out;

  // workspace carve-up (~356 MB)
  float* fws = (float*)d_ws;
  size_t off = 0;
  float* A     = fws + off; off += (size_t)NN*96;   // xw buffer
  float* Bf    = fws + off; off += (size_t)NN*96;   // aggregated buffer
  float* dinv  = fws + off; off += NN;
  float* g     = fws + off; off += NN;
  float* attP  = fws + off; off += (size_t)NB*64;
  float* attD  = fws + off; off += (size_t)NB*64;
  float* meanP = fws + off; off += (size_t)NB*96;
  float* meanD = fws + off; off += (size_t)NB*96;
  int* iws = (int*)(fws + off);
  int* segP   = iws;             iws += NB+1;
  int* segD   = iws;             iws += NB+1;
  int* degI   = iws;             iws += NN;
  int* base   = iws;             iws += NN;
  int* cursor = iws;             iws += NN;
  int* csr    = iws;             iws += EE;
  int* gc     = iws;             iws += 1;

  k_seg<<<(NB+1+255)/256, 256, 0, stream>>>(batch_p, segP);
  k_seg<<<(NB+1+255)/256, 256, 0, stream>>>(batch_d, segD);

  for (int side = 0; side < 2; ++side){
    const float* x  = side ? x_d : x_p;
    const int* src = side ? ei_d : ei_p;
    const int* dst = src + EE;
    const int* seg = side ? segD : segP;
    float* att  = side ? attD : attP;
    float* mean = side ? meanD : meanP;

    k_gate<<<NN/4, 256, 0, stream>>>(x, gW1, gb1, gW2, gb2, g);
    k_att<<<NB, 64, 0, stream>>>(x, g, seg, att);

    k_zero   <<<(NN+255)/256, 256, 0, stream>>>(degI, gc);
    k_count  <<<(EE+255)/256, 256, 0, stream>>>(dst, degI);
    k_alloc  <<<(NN+255)/256, 256, 0, stream>>>(degI, gc, base, cursor, dinv);
    k_fillcsr<<<(EE+255)/256, 256, 0, stream>>>(src, dst, cursor, csr);

    k_gemm<64,false><<<NN/64, 256, 0, stream>>>(x,  cW[side][0], A);
    k_gather<<<NN/4, dim3(96,4), 0, stream>>>(A, csr, base, degI, dinv, cB[side][0], Bf);
    k_gemm<96,true ><<<NN/64, 256, 0, stream>>>(Bf, cW[side][1], A);
    k_gather<<<NN/4, dim3(96,4), 0, stream>>>(A, csr, base, degI, dinv, cB[side][1], Bf);
    k_gemm<96,true ><<<NN/64, 256, 0, stream>>>(Bf, cW[side][2], A);
    k_gather<<<NN/4, dim3(96,4), 0, stream>>>(A, csr, base, degI, dinv, cB[side][2], Bf);
    k_mean<<<NB, 128, 0, stream>>>(Bf, seg, mean);
  }
  k_final<<<NB, 128, 0, stream>>>(meanP, meanD, attP, attD, lW0, lb0, lW1, lb1, out);
}

// Round 4
// 2674.851 us; speedup vs baseline: 1.7874x; 1.7874x over previous
//
#include <hip/hip_runtime.h>

#define NN 400000
#define EE 1600000
#define NB 8192

// ---------- segment bounds: start[b] = lower_bound(batch, b); batch is sorted ----------
__global__ void k_seg(const int* __restrict__ batch, int* __restrict__ start){
  int b = blockIdx.x*256 + threadIdx.x;
  if (b > NB) return;
  int lo = 0, hi = NN;
  while (lo < hi){ int mid = (lo+hi)>>1; if (batch[mid] < b) lo = mid+1; else hi = mid; }
  start[b] = lo;
}

// ---------- gate MLP as tiled GEMM: 64 rows/block, 4x4 micro-tile; 2nd layer fused ----------
__global__ __launch_bounds__(256) void k_gate(const float* __restrict__ x,
    const float* __restrict__ W1, const float* __restrict__ b1,
    const float* __restrict__ W2, const float* __restrict__ b2,
    float* __restrict__ g){
  __shared__ float sX[64*68];    // [k][r] transposed, pad 68
  __shared__ float sW[64*64];    // W1 [k][c]
  __shared__ float sB[128];      // b1 | W2
  __shared__ float sRed[64*17];  // per-row partials
  const int tid = threadIdx.x;
  const int r0 = blockIdx.x << 6;
  for (int i = tid; i < 4096; i += 256) sW[i] = W1[i];
  if (tid < 64) sB[tid] = b1[tid];
  else if (tid < 128) sB[tid] = W2[tid-64];
  for (int i = tid; i < 4096; i += 256){     // coalesced read of 64x64 tile
    int r = i >> 6, k = i & 63;
    sX[k*68 + r] = x[(size_t)r0*64 + i];
  }
  __syncthreads();
  const int tx = tid & 15;   // cols tx*4..+3
  const int ty = tid >> 4;   // rows ty*4..+3
  float acc[4][4];
  #pragma unroll
  for (int i = 0; i < 4; ++i)
    #pragma unroll
    for (int j = 0; j < 4; ++j) acc[i][j] = 0.f;
  for (int k = 0; k < 64; ++k){
    float a[4], w[4];
    #pragma unroll
    for (int i = 0; i < 4; ++i) a[i] = sX[k*68 + ty*4 + i];
    #pragma unroll
    for (int j = 0; j < 4; ++j) w[j] = sW[k*64 + tx*4 + j];
    #pragma unroll
    for (int i = 0; i < 4; ++i)
      #pragma unroll
      for (int j = 0; j < 4; ++j)
        acc[i][j] = fmaf(a[i], w[j], acc[i][j]);
  }
  #pragma unroll
  for (int i = 0; i < 4; ++i){
    float p = 0.f;
    #pragma unroll
    for (int j = 0; j < 4; ++j){
      int c = tx*4 + j;
      p = fmaf(fmaxf(acc[i][j] + sB[c], 0.f), sB[64+c], p);
    }
    sRed[(ty*4+i)*17 + tx] = p;
  }
  __syncthreads();
  if (tid < 64){
    float s = 0.f;
    #pragma unroll
    for (int j = 0; j < 16; ++j) s += sRed[tid*17 + j];
    g[r0 + tid] = s + b2[0];
  }
}

// ---------- attention pool: one wave per graph (segments contiguous: batch sorted) ----------
__global__ __launch_bounds__(64) void k_att(const float* __restrict__ x, const float* __restrict__ g,
    const int* __restrict__ start, float* __restrict__ att){
  int b = blockIdx.x, lane = threadIdx.x;
  int s0 = start[b], s1 = start[b+1];
  if (s1 <= s0){ att[b*64+lane] = 0.f; return; }
  float m = -3.0e38f;
  for (int i = s0+lane; i < s1; i += 64) m = fmaxf(m, g[i]);
  #pragma unroll
  for (int off = 32; off; off >>= 1) m = fmaxf(m, __shfl_xor(m, off));
  float s = 0.f;
  for (int i = s0+lane; i < s1; i += 64) s += expf(g[i]-m);
  #pragma unroll
  for (int off = 32; off; off >>= 1) s += __shfl_xor(s, off);
  float acc = 0.f;
  for (int i = s0; i < s1; ++i)                       // lane = feature
    acc = fmaf(expf(g[i]-m), x[(size_t)i*64+lane], acc);
  att[b*64+lane] = acc / s;
}

// ---------- CSR build (per side, reused for all 3 layers) ----------
__global__ void k_zero(int* __restrict__ degI, int* __restrict__ gc){
  int i = blockIdx.x*256 + threadIdx.x;
  if (i < NN) degI[i] = 0;
  if (i == 0) *gc = 0;
}
__global__ void k_count(const int* __restrict__ dst, int* __restrict__ degI){
  int e = blockIdx.x*256 + threadIdx.x;
  if (e < EE) atomicAdd(&degI[dst[e]], 1);
}
// bucket allocation: wave-level prefix scan, one global atomic per wave
__global__ __launch_bounds__(256) void k_alloc(const int* __restrict__ degI, int* __restrict__ gc,
    int* __restrict__ base, int* __restrict__ cursor, float* __restrict__ dinv){
  int i = blockIdx.x*256 + threadIdx.x;
  int lane = threadIdx.x & 63;
  int d = (i < NN) ? degI[i] : 0;
  int incl = d;
  #pragma unroll
  for (int off = 1; off < 64; off <<= 1){
    int t = __shfl_up(incl, off);
    if (lane >= off) incl += t;
  }
  int waveTotal = __shfl(incl, 63);
  int wbase = 0;
  if (lane == 63) wbase = atomicAdd(gc, waveTotal);
  wbase = __shfl(wbase, 63);
  if (i < NN){
    int b = wbase + incl - d;   // exclusive offset within wave
    base[i] = b; cursor[i] = b;
    dinv[i] = 1.f / sqrtf((float)d + 1.f);   // +1 self loop
  }
}
// csr2[p] = {src, dinv[src]} -- weight folded in so gathers skip the dinv lookup
__global__ void k_fillcsr(const int* __restrict__ src, const int* __restrict__ dst,
                          const float* __restrict__ dinv,
                          int* __restrict__ cursor, int2* __restrict__ csr2){
  int e = blockIdx.x*256 + threadIdx.x;
  if (e >= EE) return;
  int s = src[e];
  int p = atomicAdd(&cursor[dst[e]], 1);
  csr2[p] = make_int2(s, __float_as_int(dinv[s]));
}

// ---------- tall-skinny GEMM: out[N,96] = in[N,K] @ W[K,96]; relu fused on read ----------
template<int K, bool RELU>
__global__ __launch_bounds__(256) void k_gemm(const float* __restrict__ in,
    const float* __restrict__ W, float* __restrict__ out){
  __shared__ float sIn[K*68];   // transposed [k][row], pad 68
  __shared__ float sW[K*96];
  const int tid = threadIdx.x;
  const int r0 = blockIdx.x << 6;
  for (int i = tid; i < K*96; i += 256) sW[i] = W[i];
  for (int i = tid; i < 64*K; i += 256){
    int r = i / K, k = i - r*K;
    float v = in[(size_t)r0*K + i];
    if (RELU) v = fmaxf(v, 0.f);
    sIn[k*68 + r] = v;
  }
  __syncthreads();
  const int tx = tid & 15;   // cols tx*6 .. +5
  const int ty = tid >> 4;   // rows ty*4 .. +3
  float acc[4][6];
  #pragma unroll
  for (int i = 0; i < 4; ++i)
    #pragma unroll
    for (int j = 0; j < 6; ++j) acc[i][j] = 0.f;
  for (int k = 0; k < K; ++k){
    float a[4], w[6];
    #pragma unroll
    for (int i = 0; i < 4; ++i) a[i] = sIn[k*68 + ty*4 + i];
    #pragma unroll
    for (int j = 0; j < 6; ++j) w[j] = sW[k*96 + tx*6 + j];
    #pragma unroll
    for (int i = 0; i < 4; ++i)
      #pragma unroll
      for (int j = 0; j < 6; ++j)
        acc[i][j] = fmaf(a[i], w[j], acc[i][j]);
  }
  #pragma unroll
  for (int i = 0; i < 4; ++i){
    size_t row = r0 + ty*4 + i;
    #pragma unroll
    for (int j = 0; j < 6; ++j)
      out[row*96 + tx*6 + j] = acc[i][j];
  }
}

// ---------- GCN aggregation by gather, float4 + 4-edge batches ----------
// out[i] = bias + di*(di*xw[i] + sum_e w_e*xw[src_e]),  w_e = dinv[src]
__global__ __launch_bounds__(256) void k_gather(const float* __restrict__ xw,
    const int2* __restrict__ csr2, const int* __restrict__ base, const int* __restrict__ degI,
    const float* __restrict__ dinv, const float* __restrict__ bias, float* __restrict__ out){
  const int grp  = threadIdx.x >> 5;        // 8 nodes per block
  const int lane = threadIdx.x & 31;        // lanes 0..23 carry float4 features
  const int i = (blockIdx.x << 3) + grp;
  const bool act = lane < 24;
  const float4* __restrict__ xw4 = (const float4*)xw;
  const float di = dinv[i];
  const int b0 = base[i], cnt = degI[i];
  float4 s = make_float4(0.f,0.f,0.f,0.f);
  if (act){
    float4 v = xw4[(size_t)i*24 + lane];
    s.x = di*v.x; s.y = di*v.y; s.z = di*v.z; s.w = di*v.w;
  }
  int t = 0;
  for (; t+4 <= cnt; t += 4){
    int2 e0 = csr2[b0+t], e1 = csr2[b0+t+1], e2 = csr2[b0+t+2], e3 = csr2[b0+t+3];
    if (act){
      float4 v0 = xw4[(size_t)e0.x*24 + lane];
      float4 v1 = xw4[(size_t)e1.x*24 + lane];
      float4 v2 = xw4[(size_t)e2.x*24 + lane];
      float4 v3 = xw4[(size_t)e3.x*24 + lane];
      float w0 = __int_as_float(e0.y), w1 = __int_as_float(e1.y);
      float w2 = __int_as_float(e2.y), w3 = __int_as_float(e3.y);
      s.x = fmaf(w0,v0.x, fmaf(w1,v1.x, fmaf(w2,v2.x, fmaf(w3,v3.x, s.x))));
      s.y = fmaf(w0,v0.y, fmaf(w1,v1.y, fmaf(w2,v2.y, fmaf(w3,v3.y, s.y))));
      s.z = fmaf(w0,v0.z, fmaf(w1,v1.z, fmaf(w2,v2.z, fmaf(w3,v3.z, s.z))));
      s.w = fmaf(w0,v0.w, fmaf(w1,v1.w, fmaf(w2,v2.w, fmaf(w3,v3.w, s.w))));
    }
  }
  for (; t < cnt; ++t){
    int2 e = csr2[b0+t];
    if (act){
      float4 v = xw4[(size_t)e.x*24 + lane];
      float w = __int_as_float(e.y);
      s.x = fmaf(w,v.x,s.x); s.y = fmaf(w,v.y,s.y);
      s.z = fmaf(w,v.z,s.z); s.w = fmaf(w,v.w,s.w);
    }
  }
  if (act){
    float4 bb = ((const float4*)bias)[lane];
    float4 r;
    r.x = fmaf(di, s.x, bb.x); r.y = fmaf(di, s.y, bb.y);
    r.z = fmaf(di, s.z, bb.z); r.w = fmaf(di, s.w, bb.w);
    ((float4*)out)[(size_t)i*24 + lane] = r;
  }
}

// ---------- mean pool ----------
__global__ __launch_bounds__(128) void k_mean(const float* __restrict__ h,
    const int* __restrict__ start, float* __restrict__ mean){
  int b = blockIdx.x, f = threadIdx.x;
  if (f >= 96) return;
  int s0 = start[b], s1 = start[b+1];
  float acc = 0.f;
  for (int i = s0; i < s1; ++i) acc += h[(size_t)i*96+f];
  mean[b*96+f] = acc / fmaxf((float)(s1-s0), 1.f);
}

// ---------- final MLP: relu(cat@W0+b0)@W1+b1 ; fp32 output ----------
__global__ __launch_bounds__(128) void k_final(const float* __restrict__ meanP, const float* __restrict__ meanD,
    const float* __restrict__ attP, const float* __restrict__ attD,
    const float* __restrict__ W0, const float* __restrict__ b0,
    const float* __restrict__ W1, const float* __restrict__ b1,
    float* __restrict__ out){
  __shared__ float cat[320];
  __shared__ float hb[96];
  int b = blockIdx.x, tid = threadIdx.x;
  if (tid < 96){ cat[tid] = meanP[b*96+tid]; cat[96+tid] = meanD[b*96+tid]; }
  if (tid < 64){ cat[192+tid] = attP[b*64+tid]; cat[256+tid] = attD[b*64+tid]; }
  __syncthreads();
  if (tid < 96){
    float acc = b0[tid];
    for (int k = 0; k < 320; ++k) acc = fmaf(cat[k], W0[k*96+tid], acc);
    hb[tid] = fmaxf(acc, 0.f) * W1[tid];
  }
  __syncthreads();
  if (tid == 0){
    float y = b1[0];
    for (int j = 0; j < 96; ++j) y += hb[j];
    out[b] = y;
  }
}

extern "C" void kernel_launch(void* const* d_in, const int* in_sizes, int n_in,
                              void* d_out, int out_size, void* d_ws, size_t ws_size,
                              hipStream_t stream){
  const float* x_p = (const float*)d_in[0];
  const float* x_d = (const float*)d_in[1];
  const int* ei_p = (const int*)d_in[4];    // [2,E]: row0 src, row1 dst
  const int* ei_d = (const int*)d_in[5];
  const int* batch_p = (const int*)d_in[6];
  const int* batch_d = (const int*)d_in[7];
  const float* gW1 = (const float*)d_in[8];
  const float* gb1 = (const float*)d_in[9];
  const float* gW2 = (const float*)d_in[10];
  const float* gb2 = (const float*)d_in[11];
  const float* cW[2][3] = {{(const float*)d_in[12],(const float*)d_in[14],(const float*)d_in[16]},
                           {(const float*)d_in[18],(const float*)d_in[20],(const float*)d_in[22]}};
  const float* cB[2][3] = {{(const float*)d_in[13],(const float*)d_in[15],(const float*)d_in[17]},
                           {(const float*)d_in[19],(const float*)d_in[21],(const float*)d_in[23]}};
  const float* lW0 = (const float*)d_in[24];
  const float* lb0 = (const float*)d_in[25];
  const float* lW1 = (const float*)d_in[26];
  const float* lb1 = (const float*)d_in[27];
  float* out = (float*)d_out;

  // workspace carve-up (~363 MB)
  float* fws = (float*)d_ws;
  size_t off = 0;
  float* A     = fws + off; off += (size_t)NN*96;   // xw buffer
  float* Bf    = fws + off; off += (size_t)NN*96;   // aggregated buffer
  float* dinv  = fws + off; off += NN;
  float* g     = fws + off; off += NN;
  float* attP  = fws + off; off += (size_t)NB*64;
  float* attD  = fws + off; off += (size_t)NB*64;
  float* meanP = fws + off; off += (size_t)NB*96;
  float* meanD = fws + off; off += (size_t)NB*96;
  int2* csr2  = (int2*)(fws + off);                 // 8-byte aligned (off is even)
  int* iws = (int*)(csr2 + EE);
  int* segP   = iws;             iws += NB+1;
  int* segD   = iws;             iws += NB+1;
  int* degI   = iws;             iws += NN;
  int* base   = iws;             iws += NN;
  int* cursor = iws;             iws += NN;
  int* gc     = iws;             iws += 1;

  k_seg<<<(NB+1+255)/256, 256, 0, stream>>>(batch_p, segP);
  k_seg<<<(NB+1+255)/256, 256, 0, stream>>>(batch_d, segD);

  for (int side = 0; side < 2; ++side){
    const float* x  = side ? x_d : x_p;
    const int* src = side ? ei_d : ei_p;
    const int* dst = src + EE;
    const int* seg = side ? segD : segP;
    float* att  = side ? attD : attP;
    float* mean = side ? meanD : meanP;

    k_gate<<<NN/64, 256, 0, stream>>>(x, gW1, gb1, gW2, gb2, g);
    k_att<<<NB, 64, 0, stream>>>(x, g, seg, att);

    k_zero   <<<(NN+255)/256, 256, 0, stream>>>(degI, gc);
    k_count  <<<(EE+255)/256, 256, 0, stream>>>(dst, degI);
    k_alloc  <<<(NN+255)/256, 256, 0, stream>>>(degI, gc, base, cursor, dinv);
    k_fillcsr<<<(EE+255)/256, 256, 0, stream>>>(src, dst, dinv, cursor, csr2);

    k_gemm<64,false><<<NN/64, 256, 0, stream>>>(x,  cW[side][0], A);
    k_gather<<<NN/8, 256, 0, stream>>>(A, csr2, base, degI, dinv, cB[side][0], Bf);
    k_gemm<96,true ><<<NN/64, 256, 0, stream>>>(Bf, cW[side][1], A);
    k_gather<<<NN/8, 256, 0, stream>>>(A, csr2, base, degI, dinv, cB[side][1], Bf);
    k_gemm<96,true ><<<NN/64, 256, 0, stream>>>(Bf, cW[side][2], A);
    k_gather<<<NN/8, 256, 0, stream>>>(A, csr2, base, degI, dinv, cB[side][2], Bf);
    k_mean<<<NB, 128, 0, stream>>>(Bf, seg, mean);
  }
  k_final<<<NB, 128, 0, stream>>>(meanP, meanD, attP, attD, lW0, lb0, lW1, lb1, out);
}